// Round 1
// baseline (346.729 us; speedup 1.0000x reference)
//
#include <hip/hip_runtime.h>
#include <stdint.h>

#define D_DIM 2048
#define OUT_DIM 2048
#define NTOK 16384
#define SCALING 1.0f

typedef unsigned short u16;
typedef __attribute__((ext_vector_type(8))) short s16x8;
typedef __attribute__((ext_vector_type(4))) float f32x4;

// ws layout (bytes)
#define WZ_OFF  0u           // W bf16 swizzled: 2048*2048*2 = 8388608
#define AZ_OFF  8388608u     // experts_A^T bf16 swizzled [128 er][2048 d] = 524288
#define BZ_OFF  8912896u     // experts_B^T bf16 swizzled [2048 o][128 er] = 524288
#define CZ_OFF  9437184u     // c bf16 swizzled [16384 t][128 er] = 4194304
#define W8_OFF  13631488u    // router weights f32 [16384][8] = 524288
#define WS_NEED 14155776u

__device__ inline u16 f2bf(float f) {
  union { float f; uint32_t u; } v; v.f = f;
  uint32_t u = v.u;
  u += 0x7FFFu + ((u >> 16) & 1u);   // round-to-nearest-even
  return (u16)(u >> 16);
}

// ---------------- prep kernels: cast + pre-swizzle into global ----------------
// swizzle: within each 64-elem chunk of a row, elem_col ^= (row&7)<<3
__global__ __launch_bounds__(256) void k_prep_w(const float* __restrict__ W,
                                                u16* __restrict__ Wz) {
  int idx = blockIdx.x * 256 + threadIdx.x;      // 2048*512 float4 items
  int o  = idx >> 9;
  int k0 = (idx & 511) * 4;
  const float4 v = *(const float4*)&W[(size_t)o * D_DIM + k0];
  int s = (o & 7) << 3;
  int dst = (k0 & ~63) | ((k0 & 63) ^ s);        // 4-run preserved (s has bits 3..5)
  uint32_t p0 = (uint32_t)f2bf(v.x) | ((uint32_t)f2bf(v.y) << 16);
  uint32_t p1 = (uint32_t)f2bf(v.z) | ((uint32_t)f2bf(v.w) << 16);
  *(uint2*)&Wz[(size_t)o * D_DIM + dst] = make_uint2(p0, p1);
}

__global__ __launch_bounds__(256) void k_prep_a(const float* __restrict__ A,
                                                u16* __restrict__ Az) {
  int idx = blockIdx.x * 256 + threadIdx.x;      // 8*2048*16 = 262144
  float v = A[idx];
  int r = idx & 15;
  int d = (idx >> 4) & 2047;
  int e = idx >> 15;
  int er = e * 16 + r;
  int s = (er & 7) << 3;
  int dst = (d & ~63) | ((d & 63) ^ s);
  Az[(size_t)er * D_DIM + dst] = f2bf(v);
}

__global__ __launch_bounds__(256) void k_prep_b(const float* __restrict__ Bf,
                                                u16* __restrict__ Bz) {
  int idx = blockIdx.x * 256 + threadIdx.x;      // 128*2048 = 262144
  float v = Bf[idx];
  int er = idx >> 11;
  int o  = idx & 2047;
  int s = (o & 7) << 3;
  int dst = (er & 64) | ((er & 63) ^ s);
  Bz[(size_t)o * 128 + dst] = f2bf(v);
}

// ---------------- router: f32 logits, top-2, softmax ----------------
__global__ __launch_bounds__(256) void k_router(const float* __restrict__ x,
                                                const float* __restrict__ rw,
                                                float* __restrict__ w8) {
  int lane = threadIdx.x & 63, wid = threadIdx.x >> 6;
  int t = blockIdx.x * 4 + wid;
  const float* xr = x + (size_t)t * D_DIM;
  float4 xv[8];
#pragma unroll
  for (int j = 0; j < 8; ++j) xv[j] = *(const float4*)&xr[j * 256 + lane * 4];
  float lg[8];
#pragma unroll
  for (int e = 0; e < 8; ++e) {
    float a = 0.f;
#pragma unroll
    for (int j = 0; j < 8; ++j) {
      float4 rv = *(const float4*)&rw[e * D_DIM + j * 256 + lane * 4];
      a = fmaf(xv[j].x, rv.x, a); a = fmaf(xv[j].y, rv.y, a);
      a = fmaf(xv[j].z, rv.z, a); a = fmaf(xv[j].w, rv.w, a);
    }
#pragma unroll
    for (int off = 32; off; off >>= 1) a += __shfl_xor(a, off, 64);
    lg[e] = a;
  }
  int i0 = 0;
#pragma unroll
  for (int e = 1; e < 8; ++e) if (lg[e] > lg[i0]) i0 = e;
  int i1 = (i0 == 0) ? 1 : 0;
#pragma unroll
  for (int e = 0; e < 8; ++e) if (e != i0 && lg[e] > lg[i1]) i1 = e;
  float e1 = expf(lg[i1] - lg[i0]);
  float inv = 1.f / (1.f + e1);
  float w0 = inv * SCALING, w1 = e1 * inv * SCALING;
  if (lane < 8)
    w8[(size_t)t * 8 + lane] = (lane == i0) ? w0 : (lane == i1) ? w1 : 0.f;
}

// ---------------- shared GEMM helpers ----------------
// stage A-tile [128 rows][64 k] from f32, cvt bf16, XOR-swizzled LDS write
__device__ inline void stageA_f32(const float* __restrict__ x, int t0, int k0,
                                  u16* Alds, int tid) {
#pragma unroll
  for (int i = 0; i < 8; ++i) {
    int f = i * 256 + tid;
    int row = f >> 4, c4 = (f & 15) * 4;
    const float4 v = *(const float4*)&x[(size_t)(t0 + row) * D_DIM + k0 + c4];
    int dst = row * 64 + (c4 ^ ((row & 7) << 3));
    uint32_t p0 = (uint32_t)f2bf(v.x) | ((uint32_t)f2bf(v.y) << 16);
    uint32_t p1 = (uint32_t)f2bf(v.z) | ((uint32_t)f2bf(v.w) << 16);
    *(uint2*)&Alds[dst] = make_uint2(p0, p1);
  }
}

// stage [128 rows][64] tile from pre-swizzled bf16 global, linear LDS dest
__device__ inline void stage_bf16(const u16* __restrict__ src, int r0, int lds_,
                                  int c0, u16* lds, int tid) {
#pragma unroll
  for (int i = 0; i < 4; ++i) {
    int f = i * 256 + tid;
    int row = f >> 3, c8 = (f & 7) * 8;
    const uint4 v = *(const uint4*)&src[(size_t)(r0 + row) * lds_ + c0 + c8];
    *(uint4*)&lds[row * 64 + c8] = v;
  }
}

__device__ inline void mfma_chunk(const u16* Alds, const u16* Blds,
                                  int wm, int wn, int lane, f32x4 acc[4][4]) {
#pragma unroll
  for (int kk = 0; kk < 2; ++kk) {
    s16x8 af[4], bf[4];
    int ce = (lane >> 4) * 8 + kk * 32;
#pragma unroll
    for (int mf = 0; mf < 4; ++mf) {
      int row = wm * 64 + mf * 16 + (lane & 15);
      af[mf] = *(const s16x8*)&Alds[row * 64 + (ce ^ ((row & 7) << 3))];
    }
#pragma unroll
    for (int nf = 0; nf < 4; ++nf) {
      int row = wn * 64 + nf * 16 + (lane & 15);
      bf[nf] = *(const s16x8*)&Blds[row * 64 + (ce ^ ((row & 7) << 3))];
    }
#pragma unroll
    for (int mf = 0; mf < 4; ++mf)
#pragma unroll
      for (int nf = 0; nf < 4; ++nf)
        acc[mf][nf] = __builtin_amdgcn_mfma_f32_16x16x32_bf16(
            af[mf], bf[nf], acc[mf][nf], 0, 0, 0);
  }
}

// ---------------- lora-down: c = (x @ A_all) * w8, output pre-swizzled bf16 ----
__global__ __launch_bounds__(256) void k_lora(const float* __restrict__ x,
                                              const u16* __restrict__ Az,
                                              const float* __restrict__ w8,
                                              u16* __restrict__ Cz) {
  __shared__ u16 Alds[128 * 64];
  __shared__ u16 Blds[128 * 64];
  __shared__ float w8s[128 * 8];
  int tid = threadIdx.x, lane = tid & 63, wid = tid >> 6;
  int wm = wid >> 1, wn = wid & 1;
  int t0 = blockIdx.x * 128;
#pragma unroll
  for (int i = 0; i < 4; ++i) w8s[i * 256 + tid] = w8[(size_t)t0 * 8 + i * 256 + tid];
  f32x4 acc[4][4];
#pragma unroll
  for (int m = 0; m < 4; ++m)
#pragma unroll
    for (int n = 0; n < 4; ++n) acc[m][n] = (f32x4){0.f, 0.f, 0.f, 0.f};
  for (int kc = 0; kc < 32; ++kc) {
    __syncthreads();
    stageA_f32(x, t0, kc * 64, Alds, tid);
    stage_bf16(Az, 0, D_DIM, kc * 64, Blds, tid);
    __syncthreads();
    mfma_chunk(Alds, Blds, wm, wn, lane, acc);
  }
#pragma unroll
  for (int mf = 0; mf < 4; ++mf)
#pragma unroll
    for (int q = 0; q < 4; ++q) {
      int rloc = wm * 64 + mf * 16 + (lane >> 4) * 4 + q;
#pragma unroll
      for (int nf = 0; nf < 4; ++nf) {
        int er = wn * 64 + nf * 16 + (lane & 15);
        float v = acc[mf][nf][q] * w8s[rloc * 8 + (er >> 4)];
        int dst = (er & 64) | ((er & 63) ^ ((rloc & 7) << 3));
        Cz[(size_t)(t0 + rloc) * 128 + dst] = f2bf(v);
      }
    }
}

// ---------------- main fused GEMM: out = x@W^T + c@Bflat (K = 2048 + 128) ------
__global__ __launch_bounds__(256) void k_main(const float* __restrict__ x,
                                              const u16* __restrict__ Wz,
                                              const u16* __restrict__ Cz,
                                              const u16* __restrict__ Bz,
                                              float* __restrict__ out) {
  __shared__ u16 Alds[128 * 64];
  __shared__ u16 Blds[128 * 64];
  int tid = threadIdx.x, lane = tid & 63, wid = tid >> 6;
  int wm = wid >> 1, wn = wid & 1;
  int mt = blockIdx.x >> 4, nt = blockIdx.x & 15;
  int t0 = mt * 128, o0 = nt * 128;
  f32x4 acc[4][4];
#pragma unroll
  for (int m = 0; m < 4; ++m)
#pragma unroll
    for (int n = 0; n < 4; ++n) acc[m][n] = (f32x4){0.f, 0.f, 0.f, 0.f};
  for (int kc = 0; kc < 32; ++kc) {
    __syncthreads();
    stageA_f32(x, t0, kc * 64, Alds, tid);
    stage_bf16(Wz, o0, D_DIM, kc * 64, Blds, tid);
    __syncthreads();
    mfma_chunk(Alds, Blds, wm, wn, lane, acc);
  }
  for (int ke = 0; ke < 2; ++ke) {      // LoRA K-extension (er = 0..127)
    __syncthreads();
    stage_bf16(Cz, t0, 128, ke * 64, Alds, tid);
    stage_bf16(Bz, o0, 128, ke * 64, Blds, tid);
    __syncthreads();
    mfma_chunk(Alds, Blds, wm, wn, lane, acc);
  }
#pragma unroll
  for (int mf = 0; mf < 4; ++mf)
#pragma unroll
    for (int q = 0; q < 4; ++q) {
      int row = t0 + wm * 64 + mf * 16 + (lane >> 4) * 4 + q;
#pragma unroll
      for (int nf = 0; nf < 4; ++nf) {
        int col = o0 + wn * 64 + nf * 16 + (lane & 15);
        out[(size_t)row * OUT_DIM + col] = acc[mf][nf][q];
      }
    }
}

extern "C" void kernel_launch(void* const* d_in, const int* in_sizes, int n_in,
                              void* d_out, int out_size, void* d_ws, size_t ws_size,
                              hipStream_t stream) {
  const float* x  = (const float*)d_in[0];
  const float* W  = (const float*)d_in[1];
  const float* rw = (const float*)d_in[2];
  const float* eA = (const float*)d_in[3];
  const float* eB = (const float*)d_in[4];
  float* out = (float*)d_out;
  char* ws = (char*)d_ws;
  if (ws_size < WS_NEED) return;  // fail loudly via absmax rather than OOB

  u16*   Wz = (u16*)(ws + WZ_OFF);
  u16*   Az = (u16*)(ws + AZ_OFF);
  u16*   Bz = (u16*)(ws + BZ_OFF);
  u16*   Cz = (u16*)(ws + CZ_OFF);
  float* w8 = (float*)(ws + W8_OFF);

  k_prep_w<<<4096, 256, 0, stream>>>(W, Wz);
  k_prep_a<<<1024, 256, 0, stream>>>(eA, Az);
  k_prep_b<<<1024, 256, 0, stream>>>(eB, Bz);
  k_router<<<4096, 256, 0, stream>>>(x, rw, w8);
  k_lora  <<<128,  256, 0, stream>>>(x, Az, w8, Cz);
  k_main  <<<2048, 256, 0, stream>>>(x, Wz, Cz, Bz, out);
}

// Round 2
// 281.458 us; speedup vs baseline: 1.2319x; 1.2319x over previous
//
#include <hip/hip_runtime.h>
#include <stdint.h>

#define D_DIM 2048
#define OUT_DIM 2048
#define NTOK 16384
#define SCALING 1.0f

typedef unsigned short u16;
typedef __attribute__((ext_vector_type(8))) short s16x8;
typedef __attribute__((ext_vector_type(4))) float f32x4;

// ws layout (bytes)
#define WZ_OFF  0u           // W bf16 swizzled: 2048*2048*2 = 8388608
#define AZ_OFF  8388608u     // experts_A^T bf16 swizzled [128 er][2048 d]
#define BZ_OFF  8912896u     // experts_B^T bf16 swizzled [2048 o][128 er]
#define CZ_OFF  9437184u     // c bf16 swizzled [16384 t][128 er]
#define W8_OFF  13631488u    // router weights f32 [16384][8]
#define XB_OFF  14155776u    // x bf16 swizzled [16384][2048] = 67108864
#define WS_SMALL 14155776u
#define WS_BIG   81264640u

__device__ inline u16 f2bf(float f) {
  union { float f; uint32_t u; } v; v.f = f;
  uint32_t u = v.u;
  u += 0x7FFFu + ((u >> 16) & 1u);   // round-to-nearest-even
  return (u16)(u >> 16);
}

// ---------------- prep kernels: cast + pre-swizzle into global ----------------
// swizzle: within each 64-elem chunk of a row, elem_col ^= (row&7)<<3
__global__ __launch_bounds__(256) void k_prep_w(const float* __restrict__ W,
                                                u16* __restrict__ Wz) {
  int idx = blockIdx.x * 256 + threadIdx.x;      // 2048*512 float4 items
  int o  = idx >> 9;
  int k0 = (idx & 511) * 4;
  const float4 v = *(const float4*)&W[(size_t)o * D_DIM + k0];
  int s = (o & 7) << 3;
  int dst = (k0 & ~63) | ((k0 & 63) ^ s);
  uint32_t p0 = (uint32_t)f2bf(v.x) | ((uint32_t)f2bf(v.y) << 16);
  uint32_t p1 = (uint32_t)f2bf(v.z) | ((uint32_t)f2bf(v.w) << 16);
  *(uint2*)&Wz[(size_t)o * D_DIM + dst] = make_uint2(p0, p1);
}

__global__ __launch_bounds__(256) void k_prep_a(const float* __restrict__ A,
                                                u16* __restrict__ Az) {
  int idx = blockIdx.x * 256 + threadIdx.x;      // 8*2048*16 = 262144
  float v = A[idx];
  int r = idx & 15;
  int d = (idx >> 4) & 2047;
  int e = idx >> 15;
  int er = e * 16 + r;
  int s = (er & 7) << 3;
  int dst = (d & ~63) | ((d & 63) ^ s);
  Az[(size_t)er * D_DIM + dst] = f2bf(v);
}

__global__ __launch_bounds__(256) void k_prep_b(const float* __restrict__ Bf,
                                                u16* __restrict__ Bz) {
  int idx = blockIdx.x * 256 + threadIdx.x;      // 128*2048 = 262144
  float v = Bf[idx];
  int er = idx >> 11;
  int o  = idx & 2047;
  int s = (o & 7) << 3;
  int dst = (er & 64) | ((er & 63) ^ s);
  Bz[(size_t)o * 128 + dst] = f2bf(v);
}

// ------- fused router + x precast: f32 logits, top-2, softmax; xb swizzled ----
__global__ __launch_bounds__(256) void k_router_xb(const float* __restrict__ x,
                                                   const float* __restrict__ rw,
                                                   float* __restrict__ w8,
                                                   u16* __restrict__ xb) {
  int lane = threadIdx.x & 63, wid = threadIdx.x >> 6;
  int t = blockIdx.x * 4 + wid;
  const float* xr = x + (size_t)t * D_DIM;
  float4 xv[8];
#pragma unroll
  for (int j = 0; j < 8; ++j) xv[j] = *(const float4*)&xr[j * 256 + lane * 4];
  // write xb (bf16, pre-swizzled)
  int s = (t & 7) << 3;
#pragma unroll
  for (int j = 0; j < 8; ++j) {
    int c4 = j * 256 + lane * 4;
    int dst = (c4 & ~63) | ((c4 & 63) ^ s);
    uint32_t p0 = (uint32_t)f2bf(xv[j].x) | ((uint32_t)f2bf(xv[j].y) << 16);
    uint32_t p1 = (uint32_t)f2bf(xv[j].z) | ((uint32_t)f2bf(xv[j].w) << 16);
    *(uint2*)&xb[(size_t)t * D_DIM + dst] = make_uint2(p0, p1);
  }
  float lg[8];
#pragma unroll
  for (int e = 0; e < 8; ++e) {
    float a = 0.f;
#pragma unroll
    for (int j = 0; j < 8; ++j) {
      float4 rv = *(const float4*)&rw[e * D_DIM + j * 256 + lane * 4];
      a = fmaf(xv[j].x, rv.x, a); a = fmaf(xv[j].y, rv.y, a);
      a = fmaf(xv[j].z, rv.z, a); a = fmaf(xv[j].w, rv.w, a);
    }
#pragma unroll
    for (int off = 32; off; off >>= 1) a += __shfl_xor(a, off, 64);
    lg[e] = a;
  }
  int i0 = 0;
#pragma unroll
  for (int e = 1; e < 8; ++e) if (lg[e] > lg[i0]) i0 = e;
  int i1 = (i0 == 0) ? 1 : 0;
#pragma unroll
  for (int e = 0; e < 8; ++e) if (e != i0 && lg[e] > lg[i1]) i1 = e;
  float e1 = expf(lg[i1] - lg[i0]);
  float inv = 1.f / (1.f + e1);
  float w0 = inv * SCALING, w1 = e1 * inv * SCALING;
  if (lane < 8)
    w8[(size_t)t * 8 + lane] = (lane == i0) ? w0 : (lane == i1) ? w1 : 0.f;
}

// ---------------- shared GEMM helpers ----------------
// async stage [128 rows][64 cols] bf16 tile: pre-swizzled global -> linear LDS
__device__ inline void stage_g2l(const u16* __restrict__ src, int r0, int ld,
                                 int c0, u16* lds, int wid, int lane) {
#pragma unroll
  for (int i = 0; i < 4; ++i) {
    int chunk = wid * 4 + i;                    // 16 chunks of 8 rows
    const u16* g = src + (size_t)(r0 + chunk * 8 + (lane >> 3)) * ld
                       + c0 + (lane & 7) * 8;
    __builtin_amdgcn_global_load_lds(
        (const __attribute__((address_space(1))) void*)g,
        (__attribute__((address_space(3))) void*)(lds + chunk * 512),
        16, 0, 0);
  }
}

// fallback: stage A-tile from f32 with in-register cvt (swizzled LDS write)
__device__ inline void stageA_f32(const float* __restrict__ x, int t0, int k0,
                                  u16* Alds, int tid) {
#pragma unroll
  for (int i = 0; i < 8; ++i) {
    int f = i * 256 + tid;
    int row = f >> 4, c4 = (f & 15) * 4;
    const float4 v = *(const float4*)&x[(size_t)(t0 + row) * D_DIM + k0 + c4];
    int dst = row * 64 + (c4 ^ ((row & 7) << 3));
    uint32_t p0 = (uint32_t)f2bf(v.x) | ((uint32_t)f2bf(v.y) << 16);
    uint32_t p1 = (uint32_t)f2bf(v.z) | ((uint32_t)f2bf(v.w) << 16);
    *(uint2*)&Alds[dst] = make_uint2(p0, p1);
  }
}

__device__ inline void stage_bf16(const u16* __restrict__ src, int r0, int lds_,
                                  int c0, u16* lds, int tid) {
#pragma unroll
  for (int i = 0; i < 4; ++i) {
    int f = i * 256 + tid;
    int row = f >> 3, c8 = (f & 7) * 8;
    const uint4 v = *(const uint4*)&src[(size_t)(r0 + row) * lds_ + c0 + c8];
    *(uint4*)&lds[row * 64 + c8] = v;
  }
}

__device__ inline void mfma_chunk(const u16* Alds, const u16* Blds,
                                  int wm, int wn, int lane, f32x4 acc[4][4]) {
#pragma unroll
  for (int kk = 0; kk < 2; ++kk) {
    s16x8 af[4], bf[4];
    int ce = (lane >> 4) * 8 + kk * 32;
#pragma unroll
    for (int mf = 0; mf < 4; ++mf) {
      int row = wm * 64 + mf * 16 + (lane & 15);
      af[mf] = *(const s16x8*)&Alds[row * 64 + (ce ^ ((row & 7) << 3))];
    }
#pragma unroll
    for (int nf = 0; nf < 4; ++nf) {
      int row = wn * 64 + nf * 16 + (lane & 15);
      bf[nf] = *(const s16x8*)&Blds[row * 64 + (ce ^ ((row & 7) << 3))];
    }
#pragma unroll
    for (int mf = 0; mf < 4; ++mf)
#pragma unroll
      for (int nf = 0; nf < 4; ++nf)
        acc[mf][nf] = __builtin_amdgcn_mfma_f32_16x16x32_bf16(
            af[mf], bf[nf], acc[mf][nf], 0, 0, 0);
  }
}

// ---------------- lora-down (xb path): c = (xb @ A_all) * w8 -> Cz ------------
__global__ __launch_bounds__(256) void k_lora_b(const u16* __restrict__ xb,
                                                const u16* __restrict__ Az,
                                                const float* __restrict__ w8,
                                                u16* __restrict__ Cz) {
  __shared__ u16 Alds[128 * 64];
  __shared__ u16 Blds[128 * 64];
  __shared__ float w8s[128 * 8];
  int tid = threadIdx.x, lane = tid & 63, wid = tid >> 6;
  int wm = wid >> 1, wn = wid & 1;
  int t0 = blockIdx.x * 128;
#pragma unroll
  for (int i = 0; i < 4; ++i) w8s[i * 256 + tid] = w8[(size_t)t0 * 8 + i * 256 + tid];
  f32x4 acc[4][4];
#pragma unroll
  for (int m = 0; m < 4; ++m)
#pragma unroll
    for (int n = 0; n < 4; ++n) acc[m][n] = (f32x4){0.f, 0.f, 0.f, 0.f};
  for (int kc = 0; kc < 32; ++kc) {
    __syncthreads();
    stage_g2l(xb, t0, D_DIM, kc * 64, Alds, wid, lane);
    stage_g2l(Az, 0, D_DIM, kc * 64, Blds, wid, lane);
    __syncthreads();
    mfma_chunk(Alds, Blds, wm, wn, lane, acc);
  }
#pragma unroll
  for (int mf = 0; mf < 4; ++mf)
#pragma unroll
    for (int q = 0; q < 4; ++q) {
      int rloc = wm * 64 + mf * 16 + (lane >> 4) * 4 + q;
#pragma unroll
      for (int nf = 0; nf < 4; ++nf) {
        int er = wn * 64 + nf * 16 + (lane & 15);
        float v = acc[mf][nf][q] * w8s[rloc * 8 + (er >> 4)];
        int dst = (er & 64) | ((er & 63) ^ ((rloc & 7) << 3));
        Cz[(size_t)(t0 + rloc) * 128 + dst] = f2bf(v);
      }
    }
}

// ---------------- main fused GEMM (xb path) -----------------------------------
__global__ __launch_bounds__(256) void k_main_b(const u16* __restrict__ xb,
                                                const u16* __restrict__ Wz,
                                                const u16* __restrict__ Cz,
                                                const u16* __restrict__ Bz,
                                                float* __restrict__ out) {
  __shared__ u16 Alds[128 * 64];
  __shared__ u16 Blds[128 * 64];
  int tid = threadIdx.x, lane = tid & 63, wid = tid >> 6;
  int wm = wid >> 1, wn = wid & 1;
  // XCD-aware swizzle: 2048 blocks, 8 XCDs, nt-fastest within an XCD chunk
  int bid = blockIdx.x;
  int swz = (bid & 7) * 256 + (bid >> 3);
  int mt = swz >> 4, nt = swz & 15;
  int t0 = mt * 128, o0 = nt * 128;
  f32x4 acc[4][4];
#pragma unroll
  for (int m = 0; m < 4; ++m)
#pragma unroll
    for (int n = 0; n < 4; ++n) acc[m][n] = (f32x4){0.f, 0.f, 0.f, 0.f};
  for (int kc = 0; kc < 32; ++kc) {
    __syncthreads();
    stage_g2l(xb, t0, D_DIM, kc * 64, Alds, wid, lane);
    stage_g2l(Wz, o0, D_DIM, kc * 64, Blds, wid, lane);
    __syncthreads();
    mfma_chunk(Alds, Blds, wm, wn, lane, acc);
  }
  for (int ke = 0; ke < 2; ++ke) {      // LoRA K-extension (er = 0..127)
    __syncthreads();
    stage_g2l(Cz, t0, 128, ke * 64, Alds, wid, lane);
    stage_g2l(Bz, o0, 128, ke * 64, Blds, wid, lane);
    __syncthreads();
    mfma_chunk(Alds, Blds, wm, wn, lane, acc);
  }
#pragma unroll
  for (int mf = 0; mf < 4; ++mf)
#pragma unroll
    for (int q = 0; q < 4; ++q) {
      int row = t0 + wm * 64 + mf * 16 + (lane >> 4) * 4 + q;
#pragma unroll
      for (int nf = 0; nf < 4; ++nf) {
        int col = o0 + wn * 64 + nf * 16 + (lane & 15);
        out[(size_t)row * OUT_DIM + col] = acc[mf][nf][q];
      }
    }
}

// =================== fallback path (round-1, f32 A staging) ===================
__global__ __launch_bounds__(256) void k_router(const float* __restrict__ x,
                                                const float* __restrict__ rw,
                                                float* __restrict__ w8) {
  int lane = threadIdx.x & 63, wid = threadIdx.x >> 6;
  int t = blockIdx.x * 4 + wid;
  const float* xr = x + (size_t)t * D_DIM;
  float4 xv[8];
#pragma unroll
  for (int j = 0; j < 8; ++j) xv[j] = *(const float4*)&xr[j * 256 + lane * 4];
  float lg[8];
#pragma unroll
  for (int e = 0; e < 8; ++e) {
    float a = 0.f;
#pragma unroll
    for (int j = 0; j < 8; ++j) {
      float4 rv = *(const float4*)&rw[e * D_DIM + j * 256 + lane * 4];
      a = fmaf(xv[j].x, rv.x, a); a = fmaf(xv[j].y, rv.y, a);
      a = fmaf(xv[j].z, rv.z, a); a = fmaf(xv[j].w, rv.w, a);
    }
#pragma unroll
    for (int off = 32; off; off >>= 1) a += __shfl_xor(a, off, 64);
    lg[e] = a;
  }
  int i0 = 0;
#pragma unroll
  for (int e = 1; e < 8; ++e) if (lg[e] > lg[i0]) i0 = e;
  int i1 = (i0 == 0) ? 1 : 0;
#pragma unroll
  for (int e = 0; e < 8; ++e) if (e != i0 && lg[e] > lg[i1]) i1 = e;
  float e1 = expf(lg[i1] - lg[i0]);
  float inv = 1.f / (1.f + e1);
  float w0 = inv * SCALING, w1 = e1 * inv * SCALING;
  if (lane < 8)
    w8[(size_t)t * 8 + lane] = (lane == i0) ? w0 : (lane == i1) ? w1 : 0.f;
}

__global__ __launch_bounds__(256) void k_lora(const float* __restrict__ x,
                                              const u16* __restrict__ Az,
                                              const float* __restrict__ w8,
                                              u16* __restrict__ Cz) {
  __shared__ u16 Alds[128 * 64];
  __shared__ u16 Blds[128 * 64];
  __shared__ float w8s[128 * 8];
  int tid = threadIdx.x, lane = tid & 63, wid = tid >> 6;
  int wm = wid >> 1, wn = wid & 1;
  int t0 = blockIdx.x * 128;
#pragma unroll
  for (int i = 0; i < 4; ++i) w8s[i * 256 + tid] = w8[(size_t)t0 * 8 + i * 256 + tid];
  f32x4 acc[4][4];
#pragma unroll
  for (int m = 0; m < 4; ++m)
#pragma unroll
    for (int n = 0; n < 4; ++n) acc[m][n] = (f32x4){0.f, 0.f, 0.f, 0.f};
  for (int kc = 0; kc < 32; ++kc) {
    __syncthreads();
    stageA_f32(x, t0, kc * 64, Alds, tid);
    stage_bf16(Az, 0, D_DIM, kc * 64, Blds, tid);
    __syncthreads();
    mfma_chunk(Alds, Blds, wm, wn, lane, acc);
  }
#pragma unroll
  for (int mf = 0; mf < 4; ++mf)
#pragma unroll
    for (int q = 0; q < 4; ++q) {
      int rloc = wm * 64 + mf * 16 + (lane >> 4) * 4 + q;
#pragma unroll
      for (int nf = 0; nf < 4; ++nf) {
        int er = wn * 64 + nf * 16 + (lane & 15);
        float v = acc[mf][nf][q] * w8s[rloc * 8 + (er >> 4)];
        int dst = (er & 64) | ((er & 63) ^ ((rloc & 7) << 3));
        Cz[(size_t)(t0 + rloc) * 128 + dst] = f2bf(v);
      }
    }
}

__global__ __launch_bounds__(256) void k_main(const float* __restrict__ x,
                                              const u16* __restrict__ Wz,
                                              const u16* __restrict__ Cz,
                                              const u16* __restrict__ Bz,
                                              float* __restrict__ out) {
  __shared__ u16 Alds[128 * 64];
  __shared__ u16 Blds[128 * 64];
  int tid = threadIdx.x, lane = tid & 63, wid = tid >> 6;
  int wm = wid >> 1, wn = wid & 1;
  int mt = blockIdx.x >> 4, nt = blockIdx.x & 15;
  int t0 = mt * 128, o0 = nt * 128;
  f32x4 acc[4][4];
#pragma unroll
  for (int m = 0; m < 4; ++m)
#pragma unroll
    for (int n = 0; n < 4; ++n) acc[m][n] = (f32x4){0.f, 0.f, 0.f, 0.f};
  for (int kc = 0; kc < 32; ++kc) {
    __syncthreads();
    stageA_f32(x, t0, kc * 64, Alds, tid);
    stage_bf16(Wz, o0, D_DIM, kc * 64, Blds, tid);
    __syncthreads();
    mfma_chunk(Alds, Blds, wm, wn, lane, acc);
  }
  for (int ke = 0; ke < 2; ++ke) {
    __syncthreads();
    stage_bf16(Cz, t0, 128, ke * 64, Alds, tid);
    stage_bf16(Bz, o0, 128, ke * 64, Blds, tid);
    __syncthreads();
    mfma_chunk(Alds, Blds, wm, wn, lane, acc);
  }
#pragma unroll
  for (int mf = 0; mf < 4; ++mf)
#pragma unroll
    for (int q = 0; q < 4; ++q) {
      int row = t0 + wm * 64 + mf * 16 + (lane >> 4) * 4 + q;
#pragma unroll
      for (int nf = 0; nf < 4; ++nf) {
        int col = o0 + wn * 64 + nf * 16 + (lane & 15);
        out[(size_t)row * OUT_DIM + col] = acc[mf][nf][q];
      }
    }
}

extern "C" void kernel_launch(void* const* d_in, const int* in_sizes, int n_in,
                              void* d_out, int out_size, void* d_ws, size_t ws_size,
                              hipStream_t stream) {
  const float* x  = (const float*)d_in[0];
  const float* W  = (const float*)d_in[1];
  const float* rw = (const float*)d_in[2];
  const float* eA = (const float*)d_in[3];
  const float* eB = (const float*)d_in[4];
  float* out = (float*)d_out;
  char* ws = (char*)d_ws;
  if (ws_size < WS_SMALL) return;

  u16*   Wz = (u16*)(ws + WZ_OFF);
  u16*   Az = (u16*)(ws + AZ_OFF);
  u16*   Bz = (u16*)(ws + BZ_OFF);
  u16*   Cz = (u16*)(ws + CZ_OFF);
  float* w8 = (float*)(ws + W8_OFF);

  k_prep_w<<<4096, 256, 0, stream>>>(W, Wz);
  k_prep_a<<<1024, 256, 0, stream>>>(eA, Az);
  k_prep_b<<<1024, 256, 0, stream>>>(eB, Bz);

  if (ws_size >= WS_BIG) {
    u16* xb = (u16*)(ws + XB_OFF);
    k_router_xb<<<4096, 256, 0, stream>>>(x, rw, w8, xb);
    k_lora_b  <<<128,  256, 0, stream>>>(xb, Az, w8, Cz);
    k_main_b  <<<2048, 256, 0, stream>>>(xb, Wz, Cz, Bz, out);
  } else {
    k_router<<<4096, 256, 0, stream>>>(x, rw, w8);
    k_lora  <<<128,  256, 0, stream>>>(x, Az, w8, Cz);
    k_main  <<<2048, 256, 0, stream>>>(x, Wz, Cz, Bz, out);
  }
}